// Round 10
// baseline (515.535 us; speedup 1.0000x reference)
//
#include <hip/hip_runtime.h>
#include <hip/hip_fp16.h>

#define THREADS 256
#define ELL 64       // max entries per node segment (self-loop + in-degree); Poisson(16) max ~40
#define EPT 4        // edges per thread in edge_kernel
#define RSIZE 13000  // node-range size for LDS-privatized degree histogram (52 KB LDS)
#define NSLICE 64    // edge slices: grid = nr*NSLICE blocks (512 for n=100K) -> full chip

typedef _Float16 f16x8 __attribute__((ext_vector_type(8)));
typedef float f32x4 __attribute__((ext_vector_type(4)));

// ---------- fp16 pack helpers ----------
__device__ inline uint2 pack_half4(float4 v) {
    __half2 a = __floats2half2_rn(v.x, v.y);
    __half2 b = __floats2half2_rn(v.z, v.w);
    uint2 o;
    o.x = *reinterpret_cast<unsigned int*>(&a);
    o.y = *reinterpret_cast<unsigned int*>(&b);
    return o;
}
__device__ inline float4 unpack_half4(uint2 v) {
    __half2 a = *reinterpret_cast<__half2*>(&v.x);
    __half2 b = *reinterpret_cast<__half2*>(&v.y);
    float2 f0 = __half22float2(a);
    float2 f1 = __half22float2(b);
    return make_float4(f0.x, f0.y, f1.x, f1.y);
}

// ---------- preprocessing ----------

// Detect whether edge_index is int64 (odd 32-bit words all zero) or int32.
__global__ void detect_kernel(const int* __restrict__ ei, int* __restrict__ flag) {
    if (blockIdx.x == 0 && threadIdx.x == 0) {
        int nz = 0;
        for (int i = 1; i < 256; i += 2) nz |= ei[i];
        *flag = (nz == 0) ? 1 : 0;  // 1 => int64 layout
    }
}

// Self-loop at ELL slot 0, cursors.
__global__ void preinit_kernel(int* __restrict__ fill, int* __restrict__ csr, int n) {
    int i = blockIdx.x * blockDim.x + threadIdx.x;
    if (i < n) {
        fill[i] = 1;
        csr[(size_t)i * ELL] = i;
    }
}

// Source-degree histogram, LDS-privatized, ZERO global atomics.
__global__ __launch_bounds__(THREADS) void deghist_kernel(
    const int* __restrict__ ei, const int* __restrict__ flag,
    int* __restrict__ ghist, int eN, int n) {
    __shared__ int lh[RSIZE];
    const int g = blockIdx.x / NSLICE;
    const int s = blockIdx.x % NSLICE;
    const int tid = threadIdx.x;
    for (int i = tid; i < RSIZE; i += THREADS) lh[i] = 0;
    __syncthreads();

    const int lo = (int)((long long)eN * s / NSLICE);
    const int hi = (int)((long long)eN * (s + 1) / NSLICE);
    const int rbase = g * RSIZE;
    if (*flag) {
        const long long* e64 = (const long long*)ei;
        for (int idx = lo + tid; idx < hi; idx += THREADS) {
            int r = (int)e64[idx];
            unsigned int local = (unsigned int)(r - rbase);
            if (local < RSIZE) atomicAdd(&lh[local], 1);
        }
    } else {
        for (int idx = lo + tid; idx < hi; idx += THREADS) {
            int r = ei[idx];
            unsigned int local = (unsigned int)(r - rbase);
            if (local < RSIZE) atomicAdd(&lh[local], 1);
        }
    }
    __syncthreads();
    for (int i = tid; i < RSIZE; i += THREADS) {
        int node = rbase + i;
        if (node < n) ghist[(size_t)s * n + node] = lh[i];
    }
}

// ELL fill only: ONE fetch-add + one scattered store per edge.
__global__ void edge_kernel(const int* __restrict__ ei, const int* __restrict__ flag,
                            int* __restrict__ fill, int* __restrict__ csr, int eN) {
    const int t = blockIdx.x * blockDim.x + threadIdx.x;
    const int base = t * EPT;
    if (base >= eN) return;
    int r[EPT], c[EPT];
    const int m = min(EPT, eN - base);
    if (*flag) {
        const long long* e64 = (const long long*)ei;
#pragma unroll
        for (int k = 0; k < EPT; ++k)
            if (k < m) { r[k] = (int)e64[base + k]; c[k] = (int)e64[eN + base + k]; }
    } else {
#pragma unroll
        for (int k = 0; k < EPT; ++k)
            if (k < m) { r[k] = ei[base + k]; c[k] = ei[eN + base + k]; }
    }
    int pos[EPT];
#pragma unroll
    for (int k = 0; k < EPT; ++k)
        if (k < m) pos[k] = atomicAdd(&fill[c[k]], 1);
#pragma unroll
    for (int k = 0; k < EPT; ++k)
        if (k < m) csr[(size_t)c[k] * ELL + pos[k]] = r[k];
}

// dis[i] = 1/sqrt(1 + sum_s ghist[s][i])
__global__ void dis_kernel(const int* __restrict__ ghist, float* __restrict__ dis, int n) {
    int i = blockIdx.x * blockDim.x + threadIdx.x;
    if (i >= n) return;
    int deg = 1;
#pragma unroll 8
    for (int s = 0; s < NSLICE; ++s) deg += ghist[(size_t)s * n + i];
    dis[i] = 1.0f / sqrtf((float)deg);
}

// Sort each node's segment by source id (ascending), then compute
// w32[base+j] = dis[i]*dis[src_j] in sorted order and sumw[i].
// One thread per node; per-thread private LDS scratch (no syncs needed).
// Sorting makes concurrent agg gathers a narrow ascending source window
// (L2-local) and makes CSR content deterministic.
__global__ __launch_bounds__(THREADS) void sortw_kernel(
    int* __restrict__ csr, const int* __restrict__ fill,
    const float* __restrict__ dis, float* __restrict__ sumw,
    float* __restrict__ w32, int n) {
    __shared__ int buf[THREADS * ELL];   // 64 KB
    const int i = blockIdx.x * blockDim.x + threadIdx.x;
    if (i >= n) return;
    const int len = fill[i];
    const int base = i * ELL;
    int* seg = buf + threadIdx.x * ELL;
    for (int j = 0; j < len; ++j) seg[j] = csr[base + j];
    for (int a = 1; a < len; ++a) {
        int v = seg[a];
        int b = a - 1;
        while (b >= 0 && seg[b] > v) { seg[b + 1] = seg[b]; --b; }
        seg[b + 1] = v;
    }
    const float dg = dis[i];
    float t = 0.f;
    for (int j = 0; j < len; ++j) {
        int u = seg[j];
        csr[base + j] = u;
        float w = dg * dis[u];
        w32[base + j] = w;
        t += w;
    }
    sumw[i] = t;
}

// x (f32) -> H16 (fp16)
__global__ void tofp16_kernel(const float4* __restrict__ x, uint2* __restrict__ o, int total) {
    int i = blockIdx.x * blockDim.x + threadIdx.x;
    if (i < total) o[i] = pack_half4(x[i]);
}

// Pack all three W (128x128 f32, row-major [out][in]) into MFMA A-operand
// fragment order, fp16.
__global__ void wfrag_kernel(const float* __restrict__ w0, const float* __restrict__ w1,
                             const float* __restrict__ w2, _Float16* __restrict__ wf) {
    int i = blockIdx.x * blockDim.x + threadIdx.x;   // 3*8*4*64 = 6144 frags
    if (i >= 3 * 8 * 4 * 64) return;
    int lane = i & 63;
    int kt = (i >> 6) & 3;
    int nt = (i >> 8) & 7;
    int l  = i >> 11;
    const float* w = (l == 0) ? w0 : (l == 1) ? w1 : w2;
    int o  = nt * 16 + (lane & 15);
    int kb = kt * 32 + (lane >> 4) * 8;
    _Float16* dst = wf + (size_t)i * 8;
#pragma unroll
    for (int j = 0; j < 8; ++j) dst[j] = (_Float16)w[o * 128 + kb + j];
}

// ---------- per-layer kernels ----------

// A16[i] (fp16) = sum_{seg(i)} w32[j] * h16[src_j]   (f32 accumulate)
// One wave64 per node; halves interleave edges; 4x unroll per half
// -> 8 independent 256B feature gathers in flight per wave.
// Segments are SOURCE-SORTED: concurrent gathers form an ascending window.
__global__ void agg_kernel(const uint2* __restrict__ h, const int* __restrict__ csr,
                           const int* __restrict__ fill, const float* __restrict__ w32,
                           uint2* __restrict__ out, int n) {
    const int wid = blockIdx.x * (blockDim.x >> 6) + (threadIdx.x >> 6);
    const int lane = threadIdx.x & 63;
    const int half = lane >> 5;
    const int l32 = lane & 31;
    if (wid >= n) return;
    const int len = fill[wid];
    const int base = wid * ELL;

    float4 a0 = make_float4(0.f, 0.f, 0.f, 0.f);
    float4 a1 = make_float4(0.f, 0.f, 0.f, 0.f);
    float4 a2 = make_float4(0.f, 0.f, 0.f, 0.f);
    float4 a3 = make_float4(0.f, 0.f, 0.f, 0.f);
    int j = half;
    for (; j + 6 < len; j += 8) {
        int u0 = csr[base + j];
        int u1 = csr[base + j + 2];
        int u2 = csr[base + j + 4];
        int u3 = csr[base + j + 6];
        float w0 = w32[base + j];
        float w1 = w32[base + j + 2];
        float w2 = w32[base + j + 4];
        float w3 = w32[base + j + 6];
        float4 v0 = unpack_half4(h[(size_t)u0 * 32 + l32]);
        float4 v1 = unpack_half4(h[(size_t)u1 * 32 + l32]);
        float4 v2 = unpack_half4(h[(size_t)u2 * 32 + l32]);
        float4 v3 = unpack_half4(h[(size_t)u3 * 32 + l32]);
        a0.x = fmaf(w0, v0.x, a0.x); a0.y = fmaf(w0, v0.y, a0.y);
        a0.z = fmaf(w0, v0.z, a0.z); a0.w = fmaf(w0, v0.w, a0.w);
        a1.x = fmaf(w1, v1.x, a1.x); a1.y = fmaf(w1, v1.y, a1.y);
        a1.z = fmaf(w1, v1.z, a1.z); a1.w = fmaf(w1, v1.w, a1.w);
        a2.x = fmaf(w2, v2.x, a2.x); a2.y = fmaf(w2, v2.y, a2.y);
        a2.z = fmaf(w2, v2.z, a2.z); a2.w = fmaf(w2, v2.w, a2.w);
        a3.x = fmaf(w3, v3.x, a3.x); a3.y = fmaf(w3, v3.y, a3.y);
        a3.z = fmaf(w3, v3.z, a3.z); a3.w = fmaf(w3, v3.w, a3.w);
    }
    for (; j < len; j += 2) {
        int u = csr[base + j];
        float w = w32[base + j];
        float4 v = unpack_half4(h[(size_t)u * 32 + l32]);
        a0.x = fmaf(w, v.x, a0.x); a0.y = fmaf(w, v.y, a0.y);
        a0.z = fmaf(w, v.z, a0.z); a0.w = fmaf(w, v.w, a0.w);
    }
    a0.x += a1.x + a2.x + a3.x;
    a0.y += a1.y + a2.y + a3.y;
    a0.z += a1.z + a2.z + a3.z;
    a0.w += a1.w + a2.w + a3.w;

    a0.x += __shfl_xor(a0.x, 32, 64);
    a0.y += __shfl_xor(a0.y, 32, 64);
    a0.z += __shfl_xor(a0.z, 32, 64);
    a0.w += __shfl_xor(a0.w, 32, 64);

    if (half == 0) {
        out[(size_t)wid * 32 + l32] = pack_half4(a0);
    }
}

// MFMA linear layer: out[r][o] = relu( sum_k A16[r][k]*W[o][k] + sumw[r]*b[o] )
template <bool OUT16>
__global__ __launch_bounds__(THREADS) void lin_mfma_kernel(
    const _Float16* __restrict__ a16, const _Float16* __restrict__ wfrag,
    const float* __restrict__ bias, const float* __restrict__ sumw,
    float* __restrict__ outf, _Float16* __restrict__ outh, int n) {
    const int lane = threadIdx.x & 63;
    const int g = lane >> 4;       // k-octet group == feature-quad group
    const int m15 = lane & 15;     // node row within tile
    const int wavesPerBlock = blockDim.x >> 6;
    const int wave = blockIdx.x * wavesPerBlock + (threadIdx.x >> 6);
    const int nwaves = gridDim.x * wavesPerBlock;

    f16x8 wf[8][4];
#pragma unroll
    for (int nt = 0; nt < 8; ++nt)
#pragma unroll
        for (int kt = 0; kt < 4; ++kt)
            wf[nt][kt] = *reinterpret_cast<const f16x8*>(
                wfrag + ((size_t)((nt * 4 + kt) * 64 + lane)) * 8);

    const int ntiles = (n + 15) >> 4;
    for (int t = wave; t < ntiles; t += nwaves) {
        const int myrow = t * 16 + m15;
        const int rr = (myrow < n) ? myrow : (n - 1);
        const _Float16* arow = a16 + (size_t)rr * 128 + g * 8;
        f16x8 af[4];
#pragma unroll
        for (int kt = 0; kt < 4; ++kt)
            af[kt] = *reinterpret_cast<const f16x8*>(arow + kt * 32);

        f32x4 acc[8];
#pragma unroll
        for (int nt = 0; nt < 8; ++nt) acc[nt] = (f32x4){0.f, 0.f, 0.f, 0.f};
#pragma unroll
        for (int kt = 0; kt < 4; ++kt)
#pragma unroll
            for (int nt = 0; nt < 8; ++nt)
                acc[nt] = __builtin_amdgcn_mfma_f32_16x16x32_f16(
                    wf[nt][kt], af[kt], acc[nt], 0, 0, 0);

        if (myrow < n) {
            const float sw = sumw[myrow];
#pragma unroll
            for (int nt = 0; nt < 8; ++nt) {
                const float4 b4 = *reinterpret_cast<const float4*>(bias + nt * 16 + g * 4);
                float vx = fmaxf(acc[nt][0] + sw * b4.x, 0.f);
                float vy = fmaxf(acc[nt][1] + sw * b4.y, 0.f);
                float vz = fmaxf(acc[nt][2] + sw * b4.z, 0.f);
                float vw = fmaxf(acc[nt][3] + sw * b4.w, 0.f);
                size_t oidx = (size_t)myrow * 128 + nt * 16 + g * 4;
                if (OUT16) {
                    *reinterpret_cast<uint2*>(outh + oidx) =
                        pack_half4(make_float4(vx, vy, vz, vw));
                } else {
                    *reinterpret_cast<float4*>(outf + oidx) =
                        make_float4(vx, vy, vz, vw);
                }
            }
        }
    }
}

// ---------- host launch ----------

extern "C" void kernel_launch(void* const* d_in, const int* in_sizes, int n_in,
                              void* d_out, int out_size, void* d_ws, size_t ws_size,
                              hipStream_t stream) {
    const float* x  = (const float*)d_in[0];
    const int*   ei = (const int*)d_in[1];
    const float* Ws[3] = {(const float*)d_in[2], (const float*)d_in[4], (const float*)d_in[6]};
    const float* bs[3] = {(const float*)d_in[3], (const float*)d_in[5], (const float*)d_in[7]};
    const int n = in_sizes[0] / 128;
    const int e = in_sizes[1] / 2;

    char* ws = (char*)d_ws;
    size_t cur = 0;
    auto alloc = [&](size_t bytes) {
        void* p = ws + cur;
        cur = (cur + bytes + 255) & ~(size_t)255;
        return p;
    };
    uint2*     A16   = (uint2*)alloc((size_t)n * 128 * 2);       // agg out, fp16
    uint2*     H16   = (uint2*)alloc((size_t)n * 128 * 2);       // activations, fp16
    int*       csr   = (int*)  alloc((size_t)n * ELL * 4);       // ELL segments
    float*     w32   = (float*)alloc((size_t)n * ELL * 4);       // edge weights
    int*       ghist = (int*)  alloc((size_t)NSLICE * n * 4);    // partial histograms
    int*       fill  = (int*)  alloc((size_t)n * 4);
    float*     dis   = (float*)alloc((size_t)n * 4);
    float*     sumw  = (float*)alloc((size_t)n * 4);
    _Float16*  wf    = (_Float16*)alloc(3 * 8 * 4 * 64 * 8 * 2); // W fragments
    int*       flag  = (int*)  alloc(4);

    const int nr = (n + RSIZE - 1) / RSIZE;

    detect_kernel<<<1, 64, 0, stream>>>(ei, flag);
    preinit_kernel<<<(n + 255) / 256, 256, 0, stream>>>(fill, csr, n);
    deghist_kernel<<<nr * NSLICE, THREADS, 0, stream>>>(ei, flag, ghist, e, n);
    edge_kernel<<<((e + EPT - 1) / EPT + 255) / 256, 256, 0, stream>>>(
        ei, flag, fill, csr, e);
    dis_kernel<<<(n + 255) / 256, 256, 0, stream>>>(ghist, dis, n);
    sortw_kernel<<<(n + 255) / 256, 256, 0, stream>>>(csr, fill, dis, sumw, w32, n);
    tofp16_kernel<<<(n * 32 + 255) / 256, 256, 0, stream>>>((const float4*)x, H16, n * 32);
    wfrag_kernel<<<(6144 + 255) / 256, 256, 0, stream>>>(Ws[0], Ws[1], Ws[2], wf);

    for (int l = 0; l < 3; ++l) {
        agg_kernel<<<(n + 3) / 4, 256, 0, stream>>>(
            H16, csr, fill, w32, A16, n);
        const _Float16* wfl = wf + (size_t)l * 8 * 4 * 64 * 8;
        if (l < 2) {
            lin_mfma_kernel<true><<<512, THREADS, 0, stream>>>(
                (const _Float16*)A16, wfl, bs[l], sumw,
                nullptr, (_Float16*)H16, n);
        } else {
            lin_mfma_kernel<false><<<512, THREADS, 0, stream>>>(
                (const _Float16*)A16, wfl, bs[l], sumw,
                (float*)d_out, nullptr, n);
        }
    }
}

// Round 11
// 451.638 us; speedup vs baseline: 1.1415x; 1.1415x over previous
//
#include <hip/hip_runtime.h>
#include <hip/hip_fp16.h>

#define THREADS 256
#define ELL 64       // max entries per node segment (self-loop + in-degree); Poisson(16) max ~40
#define EPT 4        // edges per thread in edge-fill role
#define RSIZE 16384  // nodes per histogram range; packed u16 counters -> 32 KB LDS
#define NSLICE 64    // edge slices for histogram grid

typedef _Float16 f16x8 __attribute__((ext_vector_type(8)));
typedef float f32x4 __attribute__((ext_vector_type(4)));

// ---------- fp16 pack helpers ----------
__device__ inline uint2 pack_half4(float4 v) {
    __half2 a = __floats2half2_rn(v.x, v.y);
    __half2 b = __floats2half2_rn(v.z, v.w);
    uint2 o;
    o.x = *reinterpret_cast<unsigned int*>(&a);
    o.y = *reinterpret_cast<unsigned int*>(&b);
    return o;
}
__device__ inline float4 unpack_half4(uint2 v) {
    __half2 a = *reinterpret_cast<__half2*>(&v.x);
    __half2 b = *reinterpret_cast<__half2*>(&v.y);
    float2 f0 = __half22float2(a);
    float2 f1 = __half22float2(b);
    return make_float4(f0.x, f0.y, f1.x, f1.y);
}

// ---------- preprocessing ----------

// detect (int64 vs int32 edge layout) + self-loop slot 0 + cursor init
__global__ void preinit_kernel(const int* __restrict__ ei, int* __restrict__ flag,
                               int* __restrict__ fill, int* __restrict__ csr, int n) {
    int i = blockIdx.x * blockDim.x + threadIdx.x;
    if (i == 0) {
        int nz = 0;
        for (int k = 1; k < 256; k += 2) nz |= ei[k];
        *flag = (nz == 0) ? 1 : 0;  // 1 => int64 layout
    }
    if (i < n) {
        fill[i] = 1;
        csr[(size_t)i * ELL] = i;
    }
}

// Über-fused preprocessing: block-role split over one grid.
//  role A [0, nA):        source-degree histogram (LDS u16-packed, no global atomics)
//  role B [nA, nA+nB):    ELL fill (1 cursor fetch-add + 1 scattered 4B store / edge)
//  role C [.., +nC):      x f32 -> H16 fp16 (grid-stride copy)
//  role D [.., +24):      W fragment pack (fp16 MFMA A-operand order)
// Roles are mutually independent; B is a latency/scattered-RMW-wall workload,
// so A/C/D run inside its shadow instead of serializing after it.
__global__ __launch_bounds__(THREADS) void fused_pre_kernel(
    const int* __restrict__ ei, const int* __restrict__ flag,
    int* __restrict__ ghist, int* __restrict__ fill, int* __restrict__ csr,
    const float4* __restrict__ x, uint2* __restrict__ h16,
    const float* __restrict__ w0, const float* __restrict__ w1,
    const float* __restrict__ w2, _Float16* __restrict__ wfbuf,
    int eN, int n, int nA, int nB, int nC) {
    __shared__ unsigned int lh[RSIZE / 2];   // 32 KB packed u16 counters
    const int bid = blockIdx.x;
    const int tid = threadIdx.x;

    if (bid < nA) {
        // ---- role A: degree histogram ----
        const int g = bid / NSLICE, s = bid % NSLICE;
        for (int i = tid; i < RSIZE / 2; i += THREADS) lh[i] = 0;
        __syncthreads();
        const int lo = (int)((long long)eN * s / NSLICE);
        const int hi = (int)((long long)eN * (s + 1) / NSLICE);
        const int rbase = g * RSIZE;
        if (*flag) {
            const long long* e64 = (const long long*)ei;
            for (int idx = lo + tid; idx < hi; idx += THREADS) {
                unsigned int local = (unsigned int)((int)e64[idx] - rbase);
                if (local < RSIZE)
                    atomicAdd(&lh[local >> 1], 1u << ((local & 1) << 4));
            }
        } else {
            for (int idx = lo + tid; idx < hi; idx += THREADS) {
                unsigned int local = (unsigned int)(ei[idx] - rbase);
                if (local < RSIZE)
                    atomicAdd(&lh[local >> 1], 1u << ((local & 1) << 4));
            }
        }
        __syncthreads();
        for (int i = tid; i < RSIZE; i += THREADS) {
            int node = rbase + i;
            if (node < n)
                ghist[(size_t)s * n + node] =
                    (int)((lh[i >> 1] >> ((i & 1) << 4)) & 0xFFFFu);
        }
    } else if (bid < nA + nB) {
        // ---- role B: ELL fill ----
        const int t = (bid - nA) * THREADS + tid;
        const int base = t * EPT;
        if (base >= eN) return;
        int r[EPT], c[EPT];
        const int m = min(EPT, eN - base);
        if (*flag) {
            const long long* e64 = (const long long*)ei;
#pragma unroll
            for (int k = 0; k < EPT; ++k)
                if (k < m) { r[k] = (int)e64[base + k]; c[k] = (int)e64[eN + base + k]; }
        } else {
#pragma unroll
            for (int k = 0; k < EPT; ++k)
                if (k < m) { r[k] = ei[base + k]; c[k] = ei[eN + base + k]; }
        }
        int pos[EPT];
#pragma unroll
        for (int k = 0; k < EPT; ++k)
            if (k < m) pos[k] = atomicAdd(&fill[c[k]], 1);
#pragma unroll
        for (int k = 0; k < EPT; ++k)
            if (k < m) csr[(size_t)c[k] * ELL + pos[k]] = r[k];
    } else if (bid < nA + nB + nC) {
        // ---- role C: x -> fp16 ----
        const int total = n * 32;
        for (int i = (bid - nA - nB) * THREADS + tid; i < total; i += nC * THREADS)
            h16[i] = pack_half4(x[i]);
    } else {
        // ---- role D: W fragment pack ----
        const int i = (bid - nA - nB - nC) * THREADS + tid;   // 6144 items
        if (i < 3 * 8 * 4 * 64) {
            int lane = i & 63;
            int kt = (i >> 6) & 3;
            int nt = (i >> 8) & 7;
            int l  = i >> 11;
            const float* w = (l == 0) ? w0 : (l == 1) ? w1 : w2;
            int o  = nt * 16 + (lane & 15);
            int kb = kt * 32 + (lane >> 4) * 8;
            _Float16* dst = wfbuf + (size_t)i * 8;
#pragma unroll
            for (int j = 0; j < 8; ++j) dst[j] = (_Float16)w[o * 128 + kb + j];
        }
    }
}

// dis[i] = 1/sqrt(1 + sum_s ghist[s][i])
__global__ void dis_kernel(const int* __restrict__ ghist, float* __restrict__ dis, int n) {
    int i = blockIdx.x * blockDim.x + threadIdx.x;
    if (i >= n) return;
    int deg = 1;
#pragma unroll 8
    for (int s = 0; s < NSLICE; ++s) deg += ghist[(size_t)s * n + i];
    dis[i] = 1.0f / sqrtf((float)deg);
}

// Per node: w32[base+j] = dis[i]*dis[src_j] (sequential write) and sumw.
__global__ void sumw_kernel(const int* __restrict__ csr, const int* __restrict__ fill,
                            const float* __restrict__ dis, float* __restrict__ sumw,
                            float* __restrict__ w32, int n) {
    int i = blockIdx.x * blockDim.x + threadIdx.x;
    if (i >= n) return;
    int len = fill[i];
    const int base = i * ELL;
    const float dg = dis[i];
    float t = 0.f;
    for (int j = 0; j < len; ++j) {
        float w = dg * dis[csr[base + j]];
        w32[base + j] = w;
        t += w;
    }
    sumw[i] = t;
}

// ---------- per-layer kernels ----------

// A16[i] (fp16) = sum_{seg(i)} w32[j] * h16[src_j]   (f32 accumulate)
// One wave64 per node; halves interleave edges; 4x unroll per half.
__global__ void agg_kernel(const uint2* __restrict__ h, const int* __restrict__ csr,
                           const int* __restrict__ fill, const float* __restrict__ w32,
                           uint2* __restrict__ out, int n) {
    const int wid = blockIdx.x * (blockDim.x >> 6) + (threadIdx.x >> 6);
    const int lane = threadIdx.x & 63;
    const int half = lane >> 5;
    const int l32 = lane & 31;
    if (wid >= n) return;
    const int len = fill[wid];
    const int base = wid * ELL;

    float4 a0 = make_float4(0.f, 0.f, 0.f, 0.f);
    float4 a1 = make_float4(0.f, 0.f, 0.f, 0.f);
    float4 a2 = make_float4(0.f, 0.f, 0.f, 0.f);
    float4 a3 = make_float4(0.f, 0.f, 0.f, 0.f);
    int j = half;
    for (; j + 6 < len; j += 8) {
        int u0 = csr[base + j];
        int u1 = csr[base + j + 2];
        int u2 = csr[base + j + 4];
        int u3 = csr[base + j + 6];
        float w0 = w32[base + j];
        float w1 = w32[base + j + 2];
        float w2 = w32[base + j + 4];
        float w3 = w32[base + j + 6];
        float4 v0 = unpack_half4(h[(size_t)u0 * 32 + l32]);
        float4 v1 = unpack_half4(h[(size_t)u1 * 32 + l32]);
        float4 v2 = unpack_half4(h[(size_t)u2 * 32 + l32]);
        float4 v3 = unpack_half4(h[(size_t)u3 * 32 + l32]);
        a0.x = fmaf(w0, v0.x, a0.x); a0.y = fmaf(w0, v0.y, a0.y);
        a0.z = fmaf(w0, v0.z, a0.z); a0.w = fmaf(w0, v0.w, a0.w);
        a1.x = fmaf(w1, v1.x, a1.x); a1.y = fmaf(w1, v1.y, a1.y);
        a1.z = fmaf(w1, v1.z, a1.z); a1.w = fmaf(w1, v1.w, a1.w);
        a2.x = fmaf(w2, v2.x, a2.x); a2.y = fmaf(w2, v2.y, a2.y);
        a2.z = fmaf(w2, v2.z, a2.z); a2.w = fmaf(w2, v2.w, a2.w);
        a3.x = fmaf(w3, v3.x, a3.x); a3.y = fmaf(w3, v3.y, a3.y);
        a3.z = fmaf(w3, v3.z, a3.z); a3.w = fmaf(w3, v3.w, a3.w);
    }
    for (; j < len; j += 2) {
        int u = csr[base + j];
        float w = w32[base + j];
        float4 v = unpack_half4(h[(size_t)u * 32 + l32]);
        a0.x = fmaf(w, v.x, a0.x); a0.y = fmaf(w, v.y, a0.y);
        a0.z = fmaf(w, v.z, a0.z); a0.w = fmaf(w, v.w, a0.w);
    }
    a0.x += a1.x + a2.x + a3.x;
    a0.y += a1.y + a2.y + a3.y;
    a0.z += a1.z + a2.z + a3.z;
    a0.w += a1.w + a2.w + a3.w;

    a0.x += __shfl_xor(a0.x, 32, 64);
    a0.y += __shfl_xor(a0.y, 32, 64);
    a0.z += __shfl_xor(a0.z, 32, 64);
    a0.w += __shfl_xor(a0.w, 32, 64);

    if (half == 0) {
        out[(size_t)wid * 32 + l32] = pack_half4(a0);
    }
}

// MFMA linear layer: out[r][o] = relu( sum_k A16[r][k]*W[o][k] + sumw[r]*b[o] )
template <bool OUT16>
__global__ __launch_bounds__(THREADS) void lin_mfma_kernel(
    const _Float16* __restrict__ a16, const _Float16* __restrict__ wfrag,
    const float* __restrict__ bias, const float* __restrict__ sumw,
    float* __restrict__ outf, _Float16* __restrict__ outh, int n) {
    const int lane = threadIdx.x & 63;
    const int g = lane >> 4;       // k-octet group == feature-quad group
    const int m15 = lane & 15;     // node row within tile
    const int wavesPerBlock = blockDim.x >> 6;
    const int wave = blockIdx.x * wavesPerBlock + (threadIdx.x >> 6);
    const int nwaves = gridDim.x * wavesPerBlock;

    f16x8 wf[8][4];
#pragma unroll
    for (int nt = 0; nt < 8; ++nt)
#pragma unroll
        for (int kt = 0; kt < 4; ++kt)
            wf[nt][kt] = *reinterpret_cast<const f16x8*>(
                wfrag + ((size_t)((nt * 4 + kt) * 64 + lane)) * 8);

    const int ntiles = (n + 15) >> 4;
    for (int t = wave; t < ntiles; t += nwaves) {
        const int myrow = t * 16 + m15;
        const int rr = (myrow < n) ? myrow : (n - 1);
        const _Float16* arow = a16 + (size_t)rr * 128 + g * 8;
        f16x8 af[4];
#pragma unroll
        for (int kt = 0; kt < 4; ++kt)
            af[kt] = *reinterpret_cast<const f16x8*>(arow + kt * 32);

        f32x4 acc[8];
#pragma unroll
        for (int nt = 0; nt < 8; ++nt) acc[nt] = (f32x4){0.f, 0.f, 0.f, 0.f};
#pragma unroll
        for (int kt = 0; kt < 4; ++kt)
#pragma unroll
            for (int nt = 0; nt < 8; ++nt)
                acc[nt] = __builtin_amdgcn_mfma_f32_16x16x32_f16(
                    wf[nt][kt], af[kt], acc[nt], 0, 0, 0);

        if (myrow < n) {
            const float sw = sumw[myrow];
#pragma unroll
            for (int nt = 0; nt < 8; ++nt) {
                const float4 b4 = *reinterpret_cast<const float4*>(bias + nt * 16 + g * 4);
                float vx = fmaxf(acc[nt][0] + sw * b4.x, 0.f);
                float vy = fmaxf(acc[nt][1] + sw * b4.y, 0.f);
                float vz = fmaxf(acc[nt][2] + sw * b4.z, 0.f);
                float vw = fmaxf(acc[nt][3] + sw * b4.w, 0.f);
                size_t oidx = (size_t)myrow * 128 + nt * 16 + g * 4;
                if (OUT16) {
                    *reinterpret_cast<uint2*>(outh + oidx) =
                        pack_half4(make_float4(vx, vy, vz, vw));
                } else {
                    *reinterpret_cast<float4*>(outf + oidx) =
                        make_float4(vx, vy, vz, vw);
                }
            }
        }
    }
}

// ---------- host launch ----------

extern "C" void kernel_launch(void* const* d_in, const int* in_sizes, int n_in,
                              void* d_out, int out_size, void* d_ws, size_t ws_size,
                              hipStream_t stream) {
    const float* x  = (const float*)d_in[0];
    const int*   ei = (const int*)d_in[1];
    const float* Ws[3] = {(const float*)d_in[2], (const float*)d_in[4], (const float*)d_in[6]};
    const float* bs[3] = {(const float*)d_in[3], (const float*)d_in[5], (const float*)d_in[7]};
    const int n = in_sizes[0] / 128;
    const int e = in_sizes[1] / 2;

    char* ws = (char*)d_ws;
    size_t cur = 0;
    auto alloc = [&](size_t bytes) {
        void* p = ws + cur;
        cur = (cur + bytes + 255) & ~(size_t)255;
        return p;
    };
    uint2*     A16   = (uint2*)alloc((size_t)n * 128 * 2);       // agg out, fp16
    uint2*     H16   = (uint2*)alloc((size_t)n * 128 * 2);       // activations, fp16
    int*       csr   = (int*)  alloc((size_t)n * ELL * 4);       // ELL segments
    float*     w32   = (float*)alloc((size_t)n * ELL * 4);       // edge weights
    int*       ghist = (int*)  alloc((size_t)NSLICE * n * 4);    // partial histograms
    int*       fill  = (int*)  alloc((size_t)n * 4);
    float*     dis   = (float*)alloc((size_t)n * 4);
    float*     sumw  = (float*)alloc((size_t)n * 4);
    _Float16*  wf    = (_Float16*)alloc(3 * 8 * 4 * 64 * 8 * 2); // W fragments
    int*       flag  = (int*)  alloc(4);

    const int nr = (n + RSIZE - 1) / RSIZE;          // histogram ranges
    const int nA = nr * NSLICE;                      // deghist blocks
    const int nB = ((e + EPT - 1) / EPT + THREADS - 1) / THREADS;  // edge-fill blocks
    const int nC = 256;                              // tofp16 blocks
    const int nD = (3 * 8 * 4 * 64 + THREADS - 1) / THREADS;       // wfrag blocks

    preinit_kernel<<<(n + 255) / 256, 256, 0, stream>>>(ei, flag, fill, csr, n);
    fused_pre_kernel<<<nA + nB + nC + nD, THREADS, 0, stream>>>(
        ei, flag, ghist, fill, csr, (const float4*)x, H16,
        Ws[0], Ws[1], Ws[2], wf, e, n, nA, nB, nC);
    dis_kernel<<<(n + 255) / 256, 256, 0, stream>>>(ghist, dis, n);
    sumw_kernel<<<(n + 255) / 256, 256, 0, stream>>>(csr, fill, dis, sumw, w32, n);

    for (int l = 0; l < 3; ++l) {
        agg_kernel<<<(n + 3) / 4, 256, 0, stream>>>(
            H16, csr, fill, w32, A16, n);
        const _Float16* wfl = wf + (size_t)l * 8 * 4 * 64 * 8;
        if (l < 2) {
            lin_mfma_kernel<true><<<512, THREADS, 0, stream>>>(
                (const _Float16*)A16, wfl, bs[l], sumw,
                nullptr, (_Float16*)H16, n);
        } else {
            lin_mfma_kernel<false><<<512, THREADS, 0, stream>>>(
                (const _Float16*)A16, wfl, bs[l], sumw,
                (float*)d_out, nullptr, n);
        }
    }
}